// Round 4
// baseline (537.952 us; speedup 1.0000x reference)
//
#include <hip/hip_runtime.h>

#define BDIM 256
#define NFEAT 256
#define KDIM 16
#define NPAIR 32640   // NFEAT*(NFEAT-1)/2
#define BPB 4         // batch rows per block

typedef float v4f __attribute__((ext_vector_type(4)));
typedef unsigned v4u __attribute__((ext_vector_type(4)));

// -------- Path A: precomputed pair metadata in workspace (fast path) --------

// For every strict-upper pair (i<j) in row-major triu order:
//   sp[p] = dot(L[i,:], L[j,:])   and   ij[p] = (i<<8)|j
__global__ void setup_pairs_kernel(const float* __restrict__ L,
                                   unsigned* __restrict__ ij,
                                   float* __restrict__ sp) {
    const int i = blockIdx.x;
    const int j = threadIdx.x;
    __shared__ float Li[KDIM];
    if (j < KDIM) Li[j] = L[i * KDIM + j];
    __syncthreads();
    if (j > i) {
        float acc = 0.f;
#pragma unroll
        for (int k = 0; k < KDIM; ++k) acc += Li[k] * L[j * KDIM + k];
        const int p = i * (NFEAT - 1) - (i * (i - 1)) / 2 + (j - i - 1);
        ij[p] = ((unsigned)i << 8) | (unsigned)j;
        sp[p] = acc;
    }
}

// out[b, p] = x[b, i(p)] * x[b, j(p)] * sp[p]
__global__ __launch_bounds__(BDIM) void cross_utpm_kernel(
        const float* __restrict__ x,
        const unsigned* __restrict__ ij,
        const float* __restrict__ sp,
        float* __restrict__ out, int B) {
    __shared__ float xs[BPB][NFEAT];
    const int b0 = blockIdx.x * BPB;
    const int tid = threadIdx.x;

    // Stage BPB rows of x (one float per thread per row -> coalesced).
#pragma unroll
    for (int r = 0; r < BPB; ++r) {
        const int b = b0 + r;
        xs[r][tid] = (b < B) ? x[(size_t)b * NFEAT + tid] : 0.f;
    }
    __syncthreads();

    const v4u* ij4p = (const v4u*)ij;
    const v4f* sp4p = (const v4f*)sp;
    const int rmax = (B - b0 < BPB) ? (B - b0) : BPB;

    for (int pv = tid; pv < NPAIR / 4; pv += BDIM) {
        const v4u ij4 = ij4p[pv];
        const v4f sp4 = sp4p[pv];
        const int i0 = ij4.x >> 8, j0 = ij4.x & 255;
        const int i1 = ij4.y >> 8, j1 = ij4.y & 255;
        const int i2 = ij4.z >> 8, j2 = ij4.z & 255;
        const int i3 = ij4.w >> 8, j3 = ij4.w & 255;
        for (int r = 0; r < rmax; ++r) {
            v4f o;
            o.x = xs[r][i0] * xs[r][j0] * sp4.x;
            o.y = xs[r][i1] * xs[r][j1] * sp4.y;
            o.z = xs[r][i2] * xs[r][j2] * sp4.z;
            o.w = xs[r][i3] * xs[r][j3] * sp4.w;
            __builtin_nontemporal_store(
                o, (v4f*)(out + (size_t)(b0 + r) * NPAIR + (size_t)pv * 4));
        }
    }
}

// -------- Path B: self-contained fallback (no workspace needed) --------

__device__ __forceinline__ int row_off(int i) {
    return i * (NFEAT - 1) - (i * (i - 1)) / 2;
}

__global__ __launch_bounds__(BDIM) void cross_utpm_fallback_kernel(
        const float* __restrict__ x,
        const float* __restrict__ L,
        float* __restrict__ out, int B) {
    __shared__ float xs[BPB][NFEAT];
    __shared__ float Ls[NFEAT][KDIM];
    const int b0 = blockIdx.x * BPB;
    const int tid = threadIdx.x;

#pragma unroll
    for (int r = 0; r < BPB; ++r) {
        const int b = b0 + r;
        xs[r][tid] = (b < B) ? x[(size_t)b * NFEAT + tid] : 0.f;
    }
#pragma unroll
    for (int k = 0; k < KDIM; ++k) Ls[tid][k] = L[tid * KDIM + k];
    __syncthreads();

    const int rmax = (B - b0 < BPB) ? (B - b0) : BPB;

    for (int pv = tid; pv < NPAIR / 4; pv += BDIM) {
        int ii[4], jj[4];
        float spv[4];
#pragma unroll
        for (int e = 0; e < 4; ++e) {
            const int p = pv * 4 + e;
            int i = (int)(((2.0 * NFEAT - 1.0) -
                           sqrt((2.0 * NFEAT - 1.0) * (2.0 * NFEAT - 1.0) - 8.0 * p)) * 0.5);
            if (i < 0) i = 0;
            while (i + 1 < NFEAT && row_off(i + 1) <= p) ++i;
            while (i > 0 && row_off(i) > p) --i;
            const int j = p - row_off(i) + i + 1;
            float acc = 0.f;
#pragma unroll
            for (int k = 0; k < KDIM; ++k) acc += Ls[i][k] * Ls[j][k];
            ii[e] = i; jj[e] = j; spv[e] = acc;
        }
        for (int r = 0; r < rmax; ++r) {
            v4f o;
            o.x = xs[r][ii[0]] * xs[r][jj[0]] * spv[0];
            o.y = xs[r][ii[1]] * xs[r][jj[1]] * spv[1];
            o.z = xs[r][ii[2]] * xs[r][jj[2]] * spv[2];
            o.w = xs[r][ii[3]] * xs[r][jj[3]] * spv[3];
            __builtin_nontemporal_store(
                o, (v4f*)(out + (size_t)(b0 + r) * NPAIR + (size_t)pv * 4));
        }
    }
}

extern "C" void kernel_launch(void* const* d_in, const int* in_sizes, int n_in,
                              void* d_out, int out_size, void* d_ws, size_t ws_size,
                              hipStream_t stream) {
    const float* x = (const float*)d_in[0];         // [B, N] fp32
    const float* L = (const float*)d_in[1];         // [N, K] fp32
    float* out = (float*)d_out;                     // [B, P] fp32

    const int B = in_sizes[0] / NFEAT;              // 4096
    const int grid = (B + BPB - 1) / BPB;
    const size_t need = (size_t)NPAIR * (sizeof(unsigned) + sizeof(float));

    if (d_ws != nullptr && ws_size >= need) {
        unsigned* ij = (unsigned*)d_ws;
        float*    sp = (float*)((char*)d_ws + (size_t)NPAIR * sizeof(unsigned));
        setup_pairs_kernel<<<NFEAT, NFEAT, 0, stream>>>(L, ij, sp);
        cross_utpm_kernel<<<grid, BDIM, 0, stream>>>(x, ij, sp, out, B);
    } else {
        cross_utpm_fallback_kernel<<<grid, BDIM, 0, stream>>>(x, L, out, B);
    }
}